// Round 8
// baseline (259.456 us; speedup 1.0000x reference)
//
#include <hip/hip_runtime.h>

typedef unsigned short u16;
typedef unsigned int   u32;
typedef unsigned long long u64;
typedef __bf16 bf16x8 __attribute__((ext_vector_type(8)));
typedef float  fx4    __attribute__((ext_vector_type(4)));

__device__ __forceinline__ u16 f2bf(float f) {
    unsigned int x = __builtin_bit_cast(unsigned int, f);
    x = x + 0x7fffu + ((x >> 16) & 1u);   // round-to-nearest-even
    return (u16)(x >> 16);
}
__device__ __forceinline__ __bf16 f2bf16(float f) {
    return __builtin_bit_cast(__bf16, f2bf(f));
}
// native RNE f32->bf16
__device__ __forceinline__ u16 f2bf_fast(float f) {
    return __builtin_bit_cast(u16, (__bf16)f);
}
__device__ __forceinline__ float exp2_fast(float x) {
#if __has_builtin(__builtin_amdgcn_exp2f)
    return __builtin_amdgcn_exp2f(x);
#else
    float r;
    __asm__ volatile("v_exp_f32 %0, %1" : "=v"(r) : "v"(x));
    return r;
#endif
}
__device__ __forceinline__ int ld_nt(const int* p) {
    return __builtin_nontemporal_load(p);
}

#define MFMA16(a, b, c) __builtin_amdgcn_mfma_f32_16x16x32_bf16((a), (b), (c), 0, 0, 0)
// wave-private LDS write->read ordering (DS ops are in-order per wave)
#define WAVE_LDS_SYNC() __asm__ volatile("s_waitcnt lgkmcnt(0)" ::: "memory")

// ---------------------------------------------------------------------------
// Kernel A: WT[p][c][k] = bf16(W_p[k][c])  -> stored in first 96 KB of d_out
// ---------------------------------------------------------------------------
__global__ __launch_bounds__(256) void wt_kernel(
    const float* __restrict__ Wq, const float* __restrict__ Wk,
    const float* __restrict__ Wv, u16* __restrict__ WT)
{
    const int o = blockIdx.x * 256 + threadIdx.x;     // 0..49151
    const int p = o >> 14, rem = o & 16383, c = rem >> 7, k = rem & 127;
    const float* W = (p == 0) ? Wq : ((p == 1) ? Wk : Wv);
    WT[o] = f2bf(W[k * 128 + c]);
}

// ---------------------------------------------------------------------------
// Kernel B: Q, K, V^T fragment-major (LDS-staged coalesced stores) PLUS the
// fused adjacency bit-pack. The pack (128 MB read-once -> 4 MB bitmask) is
// pure HBM streaming; as a separate launch it cost ~25 us serial. Fused at
// the tail of this MFMA/latency-bound kernel it overlaps with other blocks'
// QKV compute. Loads are batched 8 KB/wave/burst (32 nt dwords in regs before
// the ballots) so the stream stays HBM-BW-bound at this kernel's occupancy.
// ---------------------------------------------------------------------------
__global__ __launch_bounds__(256, 2) void qkv_kernel(
    const float* __restrict__ X, const u16* __restrict__ WT,
    const float* __restrict__ bq, const float* __restrict__ bk,
    const float* __restrict__ bv,
    u16* __restrict__ Qf, u16* __restrict__ Kf, u16* __restrict__ Vf,
    const int* __restrict__ adj, u64* __restrict__ mask64)
{
    __shared__ __align__(16) u16 st[4][1024];   // 2 KB per wave staging

    const int tid  = threadIdx.x;
    const int w    = tid >> 6;
    const int lane = tid & 63;
    const int n    = lane & 15;
    const int quad = lane >> 4;
    const int gw   = blockIdx.x * 4 + w;   // 0..2047
    const int rt   = gw >> 1, ch = gw & 1;
    const int row0 = rt * 16;
    const int b    = row0 >> 11;
    const int keyb = row0 & 2047;          // multiple of 16

    u16* sw = st[w];

    // X fragments: lane holds X[row0+n][kk*32 + quad*8 + j]  (fp32 -> bf16).
    bf16x8 af[4];
    {
        const float* xr = X + (size_t)(row0 + n) * 128;
#pragma unroll
        for (int kk = 0; kk < 4; ++kk) {
            float4 f0 = *(const float4*)(xr + kk * 32 + quad * 8);
            float4 f1 = *(const float4*)(xr + kk * 32 + quad * 8 + 4);
            bf16x8 a;
            a[0] = f2bf16(f0.x); a[1] = f2bf16(f0.y); a[2] = f2bf16(f0.z); a[3] = f2bf16(f0.w);
            a[4] = f2bf16(f1.x); a[5] = f2bf16(f1.y); a[6] = f2bf16(f1.z); a[7] = f2bf16(f1.w);
            af[kk] = a;
        }
    }

    // ---- Q and K (LDS-staged, coalesced store)
    const float* Bs[2] = {bq, bk};
#pragma unroll
    for (int p = 0; p < 2; ++p) {
        const u16* wt = WT + p * 16384;
#pragma unroll
        for (int nt = 0; nt < 4; ++nt) {
            const int col0 = ch * 64 + nt * 16;
            fx4 acc = {0.f, 0.f, 0.f, 0.f};
#pragma unroll
            for (int kk = 0; kk < 4; ++kk) {
                bf16x8 bf = __builtin_bit_cast(bf16x8,
                    *(const uint4*)&wt[(col0 + n) * 128 + kk * 32 + quad * 8]);
                acc = MFMA16(af[kk], bf, acc);
            }
            const float bb = Bs[p][col0 + n];
            const int c = col0 + n;
            // local fragment index within this wave's 1024-u16 span
            const int li = ((c >> 5) & 1) * 512 + ((c >> 3) & 3) * 128 + (c & 7);
#pragma unroll
            for (int r = 0; r < 4; ++r)
                sw[li + (quad * 4 + r) * 8] = f2bf(acc[r] + bb);
        }
        WAVE_LDS_SYNC();
        u16* gbase;
        if (p == 0) {
            gbase = Qf + (((size_t)(b * 128 + (keyb >> 4)) * 4 + 2 * ch) << 9);
        } else {
            gbase = Kf + (((size_t)((b * 64 + (keyb >> 5)) * 2 + ((keyb >> 4) & 1)) * 4 + 2 * ch) << 9);
        }
        *(uint4*)(gbase + lane * 8)       = *(const uint4*)(sw + lane * 8);
        *(uint4*)(gbase + 512 + lane * 8) = *(const uint4*)(sw + 512 + lane * 8);
    }

    // ---- V^T[d][key]  (operand-swapped MFMA), LDS-staged
    {
        const u16* wtv = WT + 2 * 16384;
        const int hk    = (keyb >> 4) & 1;
        const int vtile = keyb >> 5;
#pragma unroll
        for (int d0 = 0; d0 < 4; ++d0) {
            const int dbase = ch * 64 + d0 * 16;
            fx4 acc = {0.f, 0.f, 0.f, 0.f};
#pragma unroll
            for (int kk = 0; kk < 4; ++kk) {
                bf16x8 wf = __builtin_bit_cast(bf16x8,
                    *(const uint4*)&wtv[(dbase + n) * 128 + kk * 32 + quad * 8]);
                acc = MFMA16(wf, af[kk], acc);
            }
            const int li = d0 * 256 + ((n >> 3) & 1) * 128 + (n & 7);
#pragma unroll
            for (int r = 0; r < 4; ++r)
                sw[li + (quad * 4 + r) * 8] = f2bf(acc[r] + bv[dbase + quad * 4 + r]);
        }
        WAVE_LDS_SYNC();
        const int l5 = lane >> 5, lo = lane & 31;
#pragma unroll
        for (int i = 0; i < 2; ++i) {
            const int c2 = l5 + 2 * i;
            u16* g = Vf + (((size_t)(b * 64 + vtile) * 8 + ch * 4 + c2) << 9)
                        + hk * 256 + lo * 8;
            *(uint4*)g = *(const uint4*)(sw + c2 * 256 + lo * 8);
        }
    }

    // ---- fused adjacency bit-pack: this wave packs 64 chunks of 256 ints.
    // 8 bursts x {32 nt dword loads into regs (8 KB/wave in flight), then
    // 8 x 4 ballots + stores}. Bit L of ballot = lane L's int -> exact
    // linear bit order, matching the attn consumer's u32 indexing.
    {
#pragma unroll 1
        for (int o = 0; o < 8; ++o) {
            const int it0 = gw * 64 + o * 8;    // first 256-int chunk of burst
            const int* bp = adj + (size_t)it0 * 256 + lane;
            u32 v[32];
#pragma unroll
            for (int i = 0; i < 32; ++i)
                v[i] = (u32)ld_nt(bp + i * 64);
#pragma unroll
            for (int i = 0; i < 8; ++i) {
                const u64 b0 = __ballot(v[4 * i + 0] != 0);
                const u64 b1 = __ballot(v[4 * i + 1] != 0);
                const u64 b2 = __ballot(v[4 * i + 2] != 0);
                const u64 b3 = __ballot(v[4 * i + 3] != 0);
                if (lane < 4) {
                    const u64 bv_ = (lane == 0) ? b0 : (lane == 1) ? b1
                                   : (lane == 2) ? b2 : b3;
                    mask64[(size_t)(it0 + i) * 4 + lane] = bv_;
                }
            }
        }
    }
}

// ---------------------------------------------------------------------------
// Kernel C: fused masked attention, fixed-shift softmax (unchanged from r6,
// proven 255-us-total config). In-loop adjacency = 4 u32 loads/tile from the
// 4 MB L2-resident bitmask, prefetched one tile ahead.
// ---------------------------------------------------------------------------
__global__ __launch_bounds__(256, 4) void attn_kernel(
    const u16* __restrict__ Qf, const u16* __restrict__ Kf,
    const u16* __restrict__ Vf, const u32* __restrict__ mask,
    float* __restrict__ out)
{
    __shared__ __align__(16) float mO[4][16 * 128];  // per-wave O dump (32 KB)
    __shared__ __align__(16) float ml[4][16];        // per-wave row sums
    __shared__ __align__(16) u16 pl[4][640];         // per-wave P, stride 40

    const int tid  = threadIdx.x;
    const int h    = tid >> 6;                       // key-quarter
    const int lane = tid & 63;
    const int n    = lane & 15;
    const int quad = lane >> 4;
    const int b    = blockIdx.x & 7;
    const int qt   = blockIdx.x >> 3;                // 0..127
    const int q0   = qt * 16;
    const size_t bN = (size_t)b * 2048;

    // Q fragments (A-layout): 4 coalesced 1 KB loads
    bf16x8 qf[4];
    {
        const u16* qp = Qf + ((size_t)(b * 128 + qt) << 11) + lane * 8;
#pragma unroll
        for (int kk = 0; kk < 4; ++kk)
            qf[kk] = __builtin_bit_cast(bf16x8, *(const uint4*)(qp + (kk << 9)));
    }
    const u16* Kb = Kf + ((size_t)b << 18);
    const u16* Vb = Vf + ((size_t)b << 18);

    fx4 O[8];
#pragma unroll
    for (int i = 0; i < 8; ++i) O[i] = (fx4){0.f, 0.f, 0.f, 0.f};
    fx4 Lacc = {0.f, 0.f, 0.f, 0.f};                 // row sums via MFMA-ones

    bf16x8 ONESF;
    {
        const __bf16 one = __builtin_bit_cast(__bf16, (u16)0x3F80);
#pragma unroll
        for (int j = 0; j < 8; ++j) ONESF[j] = one;
    }

    // bitmask base for this wave's 4 rows (64 u32 words per row)
    const u32* mrow = mask + (bN + q0 + quad * 4) * 64 + h * 16;
    const float C2 = 0.12751742f;   // (1/sqrt(128)) * log2(e)
    const float MB = -14427.0f;     // -10000 * log2(e): exp2 -> exactly 0.0
    u16* pw = pl[h];

    // prologue: mask words for first tile
    u32 mc[4];
#pragma unroll
    for (int r = 0; r < 4; ++r) mc[r] = mrow[r * 64];

    for (int t = 0; t < 16; ++t) {
        const int tg = h * 16 + t;
        const u16* kt_ = Kb + ((size_t)tg << 12) + lane * 8;
        const u16* vt_ = Vb + ((size_t)tg << 12) + lane * 8;

        // ---- issue K fragment loads first (S-chain head)
        bf16x8 kb[8];
#pragma unroll
        for (int kk = 0; kk < 8; ++kk)
            kb[kk] = __builtin_bit_cast(bf16x8, *(const uint4*)(kt_ + (kk << 9)));

        // ---- issue V fragment loads early: in flight across S+softmax chain
        bf16x8 vf[8];
#pragma unroll
        for (int dt = 0; dt < 8; ++dt)
            vf[dt] = __builtin_bit_cast(bf16x8, *(const uint4*)(vt_ + (dt << 9)));

        // ---- prefetch next tile's mask words (L2-resident, 4 B each)
        u32 mn_[4];
        if (t < 15) {
#pragma unroll
            for (int r = 0; r < 4; ++r) mn_[r] = mrow[r * 64 + t + 1];
        }

        // ---- S = Q K^T : 8 MFMA
        fx4 S0 = {0.f, 0.f, 0.f, 0.f}, S1 = {0.f, 0.f, 0.f, 0.f};
#pragma unroll
        for (int kk = 0; kk < 4; ++kk) {
            S0 = MFMA16(qf[kk], kb[kk], S0);
            S1 = MFMA16(qf[kk], kb[4 + kk], S1);
        }

        // ---- fixed-shift softmax numerator: p = exp2(S*C2 + bias)
#pragma unroll
        for (int r = 0; r < 4; ++r) {
            const float bias0 = ((mc[r] >> n) & 1u)        ? 0.f : MB;
            const float bias1 = ((mc[r] >> (16 + n)) & 1u) ? 0.f : MB;
            const float e0 = exp2_fast(__builtin_fmaf(S0[r], C2, bias0));
            const float e1 = exp2_fast(__builtin_fmaf(S1[r], C2, bias1));
            pw[(quad * 4 + r) * 40 + n]      = f2bf_fast(e0);
            pw[(quad * 4 + r) * 40 + 16 + n] = f2bf_fast(e1);
        }

        WAVE_LDS_SYNC();   // pl write -> read, wave-private
        bf16x8 pf = __builtin_bit_cast(bf16x8, *(const uint4*)&pw[n * 40 + quad * 8]);

        // ---- O += P V : 8 MFMA on prefetched V fragments
#pragma unroll
        for (int dt = 0; dt < 8; ++dt)
            O[dt] = MFMA16(pf, vf[dt], O[dt]);
        // ---- row sum of exactly-what-PV-sees: one MFMA, no shuffles
        Lacc = MFMA16(pf, ONESF, Lacc);

#pragma unroll
        for (int r = 0; r < 4; ++r) mc[r] = mn_[r];
    }

    // ---- 4-way merge across key-quarters (one barrier), ELU, store
#pragma unroll
    for (int r = 0; r < 4; ++r) {
        const int row = quad * 4 + r;
        if (n == 0) ml[h][row] = Lacc[r];
#pragma unroll
        for (int dt = 0; dt < 8; ++dt)
            mO[h][row * 128 + dt * 16 + n] = O[dt][r];
    }
    __syncthreads();

#pragma unroll
    for (int r = 0; r < 4; ++r) {
        const int row = quad * 4 + r;
        const float L = ml[0][row] + ml[1][row] + ml[2][row] + ml[3][row];
        const float linv = 1.f / L;
        float* po = out + (bN + q0 + row) * 128;
#pragma unroll
        for (int dti = 0; dti < 2; ++dti) {
            const int dt = h * 2 + dti;
            float o = 0.f;
#pragma unroll
            for (int g = 0; g < 4; ++g) o += mO[g][row * 128 + dt * 16 + n];
            const float hh = o * linv;
            po[dt * 16 + n] = (hh > 0.f) ? hh : (__expf(hh) - 1.f);
        }
    }
}

// ---------------------------------------------------------------------------
extern "C" void kernel_launch(void* const* d_in, const int* in_sizes, int n_in,
                              void* d_out, int out_size, void* d_ws, size_t ws_size,
                              hipStream_t stream) {
    (void)in_sizes; (void)n_in; (void)out_size; (void)ws_size;
    const float* X   = (const float*)d_in[0];
    const int*   adj = (const int*)d_in[1];
    const float* Wq  = (const float*)d_in[2];
    const float* bq  = (const float*)d_in[3];
    const float* Wk  = (const float*)d_in[4];
    const float* bk  = (const float*)d_in[5];
    const float* Wv  = (const float*)d_in[6];
    const float* bv  = (const float*)d_in[7];
    float* out = (float*)d_out;

    u16* WT   = (u16*)d_out;                     // 96 KB scratch, overwritten by attn
    u16* Qf   = (u16*)d_ws;                      // 4 MB fragment-major Q
    u16* Kf   = Qf + (size_t)16384 * 128;        // 4 MB fragment-major K
    u16* Vf   = Kf + (size_t)16384 * 128;        // 4 MB fragment-major V^T
    u32* mask = (u32*)(Vf + (size_t)16384 * 128);// 4 MB adjacency bitmask

    wt_kernel<<<192, 256, 0, stream>>>(Wq, Wk, Wv, WT);
    qkv_kernel<<<512, 256, 0, stream>>>(X, WT, bq, bk, bv, Qf, Kf, Vf,
                                        adj, (u64*)mask);
    attn_kernel<<<1024, 256, 0, stream>>>(Qf, Kf, Vf, mask, out);
}

// Round 10
// 250.383 us; speedup vs baseline: 1.0362x; 1.0362x over previous
//
#include <hip/hip_runtime.h>

typedef unsigned short u16;
typedef unsigned int   u32;
typedef unsigned long long u64;
typedef __bf16 bf16x8 __attribute__((ext_vector_type(8)));
typedef float  fx4    __attribute__((ext_vector_type(4)));

__device__ __forceinline__ u16 f2bf(float f) {
    unsigned int x = __builtin_bit_cast(unsigned int, f);
    x = x + 0x7fffu + ((x >> 16) & 1u);   // round-to-nearest-even
    return (u16)(x >> 16);
}
__device__ __forceinline__ __bf16 f2bf16(float f) {
    return __builtin_bit_cast(__bf16, f2bf(f));
}
// native RNE f32->bf16
__device__ __forceinline__ u16 f2bf_fast(float f) {
    return __builtin_bit_cast(u16, (__bf16)f);
}
__device__ __forceinline__ float exp2_fast(float x) {
#if __has_builtin(__builtin_amdgcn_exp2f)
    return __builtin_amdgcn_exp2f(x);
#else
    float r;
    __asm__ volatile("v_exp_f32 %0, %1" : "=v"(r) : "v"(x));
    return r;
#endif
}
__device__ __forceinline__ int ld_nt(const int* p) {
    return __builtin_nontemporal_load(p);
}

#define MFMA16(a, b, c) __builtin_amdgcn_mfma_f32_16x16x32_bf16((a), (b), (c), 0, 0, 0)
// wave-private LDS write->read ordering (DS ops are in-order per wave)
#define WAVE_LDS_SYNC() __asm__ volatile("s_waitcnt lgkmcnt(0)" ::: "memory")

// ---------------------------------------------------------------------------
// Kernel A: WT[p][c][k] = bf16(W_p[k][c])  -> stored in first 96 KB of d_out
// ---------------------------------------------------------------------------
__global__ __launch_bounds__(256) void wt_kernel(
    const float* __restrict__ Wq, const float* __restrict__ Wk,
    const float* __restrict__ Wv, u16* __restrict__ WT)
{
    const int o = blockIdx.x * 256 + threadIdx.x;     // 0..49151
    const int p = o >> 14, rem = o & 16383, c = rem >> 7, k = rem & 127;
    const float* W = (p == 0) ? Wq : ((p == 1) ? Wk : Wv);
    WT[o] = f2bf(W[k * 128 + c]);
}

// ---------------------------------------------------------------------------
// Kernel B: Q, K, V^T fragment-major (r6 form: LDS-staged coalesced stores,
// no pack tail -- r7 showed the fused tail serializes at 2 blocks/CU).
// ---------------------------------------------------------------------------
__global__ __launch_bounds__(256, 2) void qkv_kernel(
    const float* __restrict__ X, const u16* __restrict__ WT,
    const float* __restrict__ bq, const float* __restrict__ bk,
    const float* __restrict__ bv,
    u16* __restrict__ Qf, u16* __restrict__ Kf, u16* __restrict__ Vf)
{
    __shared__ __align__(16) u16 st[4][1024];   // 2 KB per wave staging

    const int tid  = threadIdx.x;
    const int w    = tid >> 6;
    const int lane = tid & 63;
    const int n    = lane & 15;
    const int quad = lane >> 4;
    const int gw   = blockIdx.x * 4 + w;   // 0..2047
    const int rt   = gw >> 1, ch = gw & 1;
    const int row0 = rt * 16;
    const int b    = row0 >> 11;
    const int keyb = row0 & 2047;          // multiple of 16

    u16* sw = st[w];

    // X fragments: lane holds X[row0+n][kk*32 + quad*8 + j]  (fp32 -> bf16).
    bf16x8 af[4];
    {
        const float* xr = X + (size_t)(row0 + n) * 128;
#pragma unroll
        for (int kk = 0; kk < 4; ++kk) {
            float4 f0 = *(const float4*)(xr + kk * 32 + quad * 8);
            float4 f1 = *(const float4*)(xr + kk * 32 + quad * 8 + 4);
            bf16x8 a;
            a[0] = f2bf16(f0.x); a[1] = f2bf16(f0.y); a[2] = f2bf16(f0.z); a[3] = f2bf16(f0.w);
            a[4] = f2bf16(f1.x); a[5] = f2bf16(f1.y); a[6] = f2bf16(f1.z); a[7] = f2bf16(f1.w);
            af[kk] = a;
        }
    }

    // ---- Q and K (LDS-staged, coalesced store)
    const float* Bs[2] = {bq, bk};
#pragma unroll
    for (int p = 0; p < 2; ++p) {
        const u16* wt = WT + p * 16384;
#pragma unroll
        for (int nt = 0; nt < 4; ++nt) {
            const int col0 = ch * 64 + nt * 16;
            fx4 acc = {0.f, 0.f, 0.f, 0.f};
#pragma unroll
            for (int kk = 0; kk < 4; ++kk) {
                bf16x8 bf = __builtin_bit_cast(bf16x8,
                    *(const uint4*)&wt[(col0 + n) * 128 + kk * 32 + quad * 8]);
                acc = MFMA16(af[kk], bf, acc);
            }
            const float bb = Bs[p][col0 + n];
            const int c = col0 + n;
            // local fragment index within this wave's 1024-u16 span
            const int li = ((c >> 5) & 1) * 512 + ((c >> 3) & 3) * 128 + (c & 7);
#pragma unroll
            for (int r = 0; r < 4; ++r)
                sw[li + (quad * 4 + r) * 8] = f2bf(acc[r] + bb);
        }
        WAVE_LDS_SYNC();
        u16* gbase;
        if (p == 0) {
            gbase = Qf + (((size_t)(b * 128 + (keyb >> 4)) * 4 + 2 * ch) << 9);
        } else {
            gbase = Kf + (((size_t)((b * 64 + (keyb >> 5)) * 2 + ((keyb >> 4) & 1)) * 4 + 2 * ch) << 9);
        }
        *(uint4*)(gbase + lane * 8)       = *(const uint4*)(sw + lane * 8);
        *(uint4*)(gbase + 512 + lane * 8) = *(const uint4*)(sw + 512 + lane * 8);
    }

    // ---- V^T[d][key]  (operand-swapped MFMA), LDS-staged
    {
        const u16* wtv = WT + 2 * 16384;
        const int hk    = (keyb >> 4) & 1;
        const int vtile = keyb >> 5;
#pragma unroll
        for (int d0 = 0; d0 < 4; ++d0) {
            const int dbase = ch * 64 + d0 * 16;
            fx4 acc = {0.f, 0.f, 0.f, 0.f};
#pragma unroll
            for (int kk = 0; kk < 4; ++kk) {
                bf16x8 wf = __builtin_bit_cast(bf16x8,
                    *(const uint4*)&wtv[(dbase + n) * 128 + kk * 32 + quad * 8]);
                acc = MFMA16(wf, af[kk], acc);
            }
            const int li = d0 * 256 + ((n >> 3) & 1) * 128 + (n & 7);
#pragma unroll
            for (int r = 0; r < 4; ++r)
                sw[li + (quad * 4 + r) * 8] = f2bf(acc[r] + bv[dbase + quad * 4 + r]);
        }
        WAVE_LDS_SYNC();
        const int l5 = lane >> 5, lo = lane & 31;
#pragma unroll
        for (int i = 0; i < 2; ++i) {
            const int c2 = l5 + 2 * i;
            u16* g = Vf + (((size_t)(b * 64 + vtile) * 8 + ch * 4 + c2) << 9)
                        + hk * 256 + lo * 8;
            *(uint4*)g = *(const uint4*)(sw + c2 * 256 + lo * 8);
        }
    }
}

// ---------------------------------------------------------------------------
// Kernel C: fused masked attention. The adjacency bit-pack is fused into each
// block's PROLOGUE. Wave h ballot-packs its key-quarter of this block's 16
// q-rows (32 KB of adj, 32-load reg bursts, nt) into 1 KB of LDS, overlaid on
// mO[h] (epilogue-only; per-wave self-overlay => race-free). The main loop
// reads mask words from LDS (quad-uniform broadcast reads). Removes the
// separate pack kernel (~25 us serial) and the 8 MB mask round-trip; the adj
// HBM stream now overlaps other resident blocks' compute.
// ---------------------------------------------------------------------------
__global__ __launch_bounds__(256, 4) void attn_kernel(
    const u16* __restrict__ Qf, const u16* __restrict__ Kf,
    const u16* __restrict__ Vf, const int* __restrict__ adj,
    float* __restrict__ out)
{
    __shared__ __align__(16) float mO[4][16 * 128];  // per-wave O dump (32 KB)
    __shared__ __align__(16) float ml[4][16];        // per-wave row sums
    __shared__ __align__(16) u16 pl[4][640];         // per-wave P, stride 40

    const int tid  = threadIdx.x;
    const int h    = tid >> 6;                       // key-quarter
    const int lane = tid & 63;
    const int n    = lane & 15;
    const int quad = lane >> 4;
    const int b    = blockIdx.x & 7;
    const int qt   = blockIdx.x >> 3;                // 0..127
    const int q0   = qt * 16;
    const size_t bN = (size_t)b * 2048;

    // ---- adj pack prologue: mask words [row(16)][word(16)] in u32, 1 KB,
    // overlaid on this wave's mO[h] (only used in epilogue).
    u32* mlds = (u32*)&mO[h][0];
    {
        const int* ab = adj + (bN + q0) * 2048 + h * 512 + lane;
#pragma unroll 1
        for (int rb = 0; rb < 4; ++rb) {             // 4 bursts x 4 rows
            int v[32];
#pragma unroll
            for (int i = 0; i < 32; ++i) {
                const int r = rb * 4 + (i >> 3), c = i & 7;
                v[i] = ld_nt(ab + (size_t)r * 2048 + c * 64);
            }
#pragma unroll
            for (int i = 0; i < 32; ++i) {
                const u64 bl = __ballot(v[i] != 0);  // bit L = key c*64+L
                const int r = rb * 4 + (i >> 3), c = i & 7;
                if (lane == 0)
                    *(u64*)&mlds[r * 16 + c * 2] = bl;
            }
        }
    }
    WAVE_LDS_SYNC();   // wave-private LDS: pack visible to this wave's reads

    // Q fragments (A-layout): 4 coalesced 1 KB loads (after prologue to keep
    // burst-load register pressure low)
    bf16x8 qf[4];
    {
        const u16* qp = Qf + ((size_t)(b * 128 + qt) << 11) + lane * 8;
#pragma unroll
        for (int kk = 0; kk < 4; ++kk)
            qf[kk] = __builtin_bit_cast(bf16x8, *(const uint4*)(qp + (kk << 9)));
    }
    const u16* Kb = Kf + ((size_t)b << 18);
    const u16* Vb = Vf + ((size_t)b << 18);

    fx4 O[8];
#pragma unroll
    for (int i = 0; i < 8; ++i) O[i] = (fx4){0.f, 0.f, 0.f, 0.f};
    fx4 Lacc = {0.f, 0.f, 0.f, 0.f};                 // row sums via MFMA-ones

    bf16x8 ONESF;
    {
        const __bf16 one = __builtin_bit_cast(__bf16, (u16)0x3F80);
#pragma unroll
        for (int j = 0; j < 8; ++j) ONESF[j] = one;
    }

    const float C2 = 0.12751742f;   // (1/sqrt(128)) * log2(e)
    const float MB = -14427.0f;     // -10000 * log2(e): exp2 -> exactly 0.0
    u16* pw = pl[h];

    // prologue: mask words for first tile (LDS broadcast reads)
    u32 mc[4];
#pragma unroll
    for (int r = 0; r < 4; ++r) mc[r] = mlds[(quad * 4 + r) * 16];

    for (int t = 0; t < 16; ++t) {
        const int tg = h * 16 + t;
        const u16* kt_ = Kb + ((size_t)tg << 12) + lane * 8;
        const u16* vt_ = Vb + ((size_t)tg << 12) + lane * 8;

        // ---- issue K fragment loads first (S-chain head)
        bf16x8 kb[8];
#pragma unroll
        for (int kk = 0; kk < 8; ++kk)
            kb[kk] = __builtin_bit_cast(bf16x8, *(const uint4*)(kt_ + (kk << 9)));

        // ---- issue V fragment loads early: in flight across S+softmax chain
        bf16x8 vf[8];
#pragma unroll
        for (int dt = 0; dt < 8; ++dt)
            vf[dt] = __builtin_bit_cast(bf16x8, *(const uint4*)(vt_ + (dt << 9)));

        // ---- prefetch next tile's mask words (LDS, quad-uniform broadcast)
        u32 mn_[4];
        if (t < 15) {
#pragma unroll
            for (int r = 0; r < 4; ++r) mn_[r] = mlds[(quad * 4 + r) * 16 + t + 1];
        }

        // ---- S = Q K^T : 8 MFMA
        fx4 S0 = {0.f, 0.f, 0.f, 0.f}, S1 = {0.f, 0.f, 0.f, 0.f};
#pragma unroll
        for (int kk = 0; kk < 4; ++kk) {
            S0 = MFMA16(qf[kk], kb[kk], S0);
            S1 = MFMA16(qf[kk], kb[4 + kk], S1);
        }

        // ---- fixed-shift softmax numerator: p = exp2(S*C2 + bias)
#pragma unroll
        for (int r = 0; r < 4; ++r) {
            const float bias0 = ((mc[r] >> n) & 1u)        ? 0.f : MB;
            const float bias1 = ((mc[r] >> (16 + n)) & 1u) ? 0.f : MB;
            const float e0 = exp2_fast(__builtin_fmaf(S0[r], C2, bias0));
            const float e1 = exp2_fast(__builtin_fmaf(S1[r], C2, bias1));
            pw[(quad * 4 + r) * 40 + n]      = f2bf_fast(e0);
            pw[(quad * 4 + r) * 40 + 16 + n] = f2bf_fast(e1);
        }

        WAVE_LDS_SYNC();   // pl write -> read, wave-private
        bf16x8 pf = __builtin_bit_cast(bf16x8, *(const uint4*)&pw[n * 40 + quad * 8]);

        // ---- O += P V : 8 MFMA on prefetched V fragments
#pragma unroll
        for (int dt = 0; dt < 8; ++dt)
            O[dt] = MFMA16(pf, vf[dt], O[dt]);
        // ---- row sum of exactly-what-PV-sees: one MFMA, no shuffles
        Lacc = MFMA16(pf, ONESF, Lacc);

#pragma unroll
        for (int r = 0; r < 4; ++r) mc[r] = mn_[r];
    }

    // ---- 4-way merge across key-quarters (one barrier), ELU, store
    // (mO[h] write overwrites this wave's mask region -- reads are all done)
#pragma unroll
    for (int r = 0; r < 4; ++r) {
        const int row = quad * 4 + r;
        if (n == 0) ml[h][row] = Lacc[r];
#pragma unroll
        for (int dt = 0; dt < 8; ++dt)
            mO[h][row * 128 + dt * 16 + n] = O[dt][r];
    }
    __syncthreads();

#pragma unroll
    for (int r = 0; r < 4; ++r) {
        const int row = quad * 4 + r;
        const float L = ml[0][row] + ml[1][row] + ml[2][row] + ml[3][row];
        const float linv = 1.f / L;
        float* po = out + (bN + q0 + row) * 128;
#pragma unroll
        for (int dti = 0; dti < 2; ++dti) {
            const int dt = h * 2 + dti;
            float o = 0.f;
#pragma unroll
            for (int g = 0; g < 4; ++g) o += mO[g][row * 128 + dt * 16 + n];
            const float hh = o * linv;
            po[dt * 16 + n] = (hh > 0.f) ? hh : (__expf(hh) - 1.f);
        }
    }
}

// ---------------------------------------------------------------------------
extern "C" void kernel_launch(void* const* d_in, const int* in_sizes, int n_in,
                              void* d_out, int out_size, void* d_ws, size_t ws_size,
                              hipStream_t stream) {
    (void)in_sizes; (void)n_in; (void)out_size; (void)ws_size;
    const float* X   = (const float*)d_in[0];
    const int*   adj = (const int*)d_in[1];
    const float* Wq  = (const float*)d_in[2];
    const float* bq  = (const float*)d_in[3];
    const float* Wk  = (const float*)d_in[4];
    const float* bk  = (const float*)d_in[5];
    const float* Wv  = (const float*)d_in[6];
    const float* bv  = (const float*)d_in[7];
    float* out = (float*)d_out;

    u16* WT   = (u16*)d_out;                     // 96 KB scratch, overwritten by attn
    u16* Qf   = (u16*)d_ws;                      // 4 MB fragment-major Q
    u16* Kf   = Qf + (size_t)16384 * 128;        // 4 MB fragment-major K
    u16* Vf   = Kf + (size_t)16384 * 128;        // 4 MB fragment-major V^T

    wt_kernel<<<192, 256, 0, stream>>>(Wq, Wk, Wv, WT);
    qkv_kernel<<<512, 256, 0, stream>>>(X, WT, bq, bk, bv, Qf, Kf, Vf);
    attn_kernel<<<1024, 256, 0, stream>>>(Qf, Kf, Vf, adj, out);
}